// Round 5
// baseline (256.761 us; speedup 1.0000x reference)
//
#include <hip/hip_runtime.h>

// LSSM: x_t = x_{t-1} A^T + u_t B^T ; y_t = x_t C^T + u_t D^T ; x_0 = 0
// B=16, SEQ=8192, all dims 128.
//
// R5 structure:
//  prepA..D: Kbig[j] = A^{15-j}B via log-depth batched 128^3 matmuls (S_{p+2^k} = A^{2^k} S_p),
//            plus A^16 (tree P), G=CA, H=CB+D. One block per matmul, global round-trips.
//  pass1:    E_c = U_c[16,2048] @ Kbig[2048,128]  -- pure GEMM, no barriers/LDS.
//  tree:     k_group (32 scans of 16 + 8 ident blocks -> Pg=P^16), k_top (32-step scan),
//            k_fix (rescan -> chunk entry states S, in-place over E). E/E2/S2 in bf16.
//  pass2:    per-chunk 16-step recurrence, whole-chunk u staged to LDS in prologue;
//            steps are pure LDS+MFMA with lgkm-only raw barriers; y = x_{t-1}G^T + u_t H^T.

#define SEQ 8192
#define BS  16
#define DD  128
#define CL  16
#define NC  512
#define GRP 16
#define NG  32

typedef __bf16 bf16t;
typedef __bf16 bf16x8 __attribute__((ext_vector_type(8)));
typedef __bf16 bf16x4 __attribute__((ext_vector_type(4)));
typedef float  f32x4  __attribute__((ext_vector_type(4)));

#define MFMA(a,b,c) __builtin_amdgcn_mfma_f32_16x16x32_bf16(a,b,c,0,0,0)

__device__ __forceinline__ int swz(int b, int j) { return j ^ ((b & 7) << 3); }

struct Frag  { bf16x8 h[4]; bf16x8 l[4]; };
struct FragH { bf16x8 h[4]; };

// lgkm-only barrier: LDS producer-consumer sync without draining global stores
__device__ __forceinline__ void step_barrier() {
    asm volatile("s_waitcnt lgkmcnt(0)" ::: "memory");
    __builtin_amdgcn_s_barrier();
    __builtin_amdgcn_sched_barrier(0);
}

// B-operand frags of M where M[k][n] = src[n][k]  (src row-major [128][128] f32)
__device__ __forceinline__ void load_frag_T(const float* __restrict__ src, int lane, int w, Frag& f) {
    int n  = (w << 4) + (lane & 15);
    int kb = ((lane >> 4) & 3) << 3;
#pragma unroll
    for (int q = 0; q < 4; q++) {
        const float* p = src + n * DD + (q << 5) + kb;
#pragma unroll
        for (int e = 0; e < 8; e++) {
            float v = p[e];
            bf16t hh = (bf16t)v;
            f.h[q][e] = hh;
            f.l[q][e] = (bf16t)(v - (float)hh);
        }
    }
}

__device__ __forceinline__ void load_frag_T_h(const float* __restrict__ src, int lane, int w, FragH& f) {
    int n  = (w << 4) + (lane & 15);
    int kb = ((lane >> 4) & 3) << 3;
#pragma unroll
    for (int q = 0; q < 4; q++) {
        const float* p = src + n * DD + (q << 5) + kb;
#pragma unroll
        for (int e = 0; e < 8; e++) f.h[q][e] = (bf16t)p[e];
    }
}

// B-operand frags of M where M[k][n] = src[k][n]  (no transpose; strided gather)
__device__ __forceinline__ void load_frag_N(const float* __restrict__ src, int lane, int w, Frag& f) {
    int n  = (w << 4) + (lane & 15);
    int kb = ((lane >> 4) & 3) << 3;
#pragma unroll
    for (int q = 0; q < 4; q++) {
#pragma unroll
        for (int e = 0; e < 8; e++) {
            float v = src[((q << 5) + kb + e) * DD + n];
            bf16t hh = (bf16t)v;
            f.h[q][e] = hh;
            f.l[q][e] = (bf16t)(v - (float)hh);
        }
    }
}

// A-operand frag from swizzled LDS [16][128] bf16: lane&15 -> row b
__device__ __forceinline__ bf16x8 afrag(const bf16t* __restrict__ X, int lane, int q) {
    int b  = lane & 15;
    int j0 = (q << 5) + (((lane >> 4) & 3) << 3);
    return *(const bf16x8*)(X + b * DD + swz(b, j0));
}

// D-frag (f32x4) -> hi/lo bf16 swizzled LDS.  D layout: col=lane&15, row=(lane>>4)*4+r
__device__ __forceinline__ void put_state(bf16t* __restrict__ H, bf16t* __restrict__ L,
                                          int lane, int w, f32x4 acc) {
    int n = (w << 4) + (lane & 15);
#pragma unroll
    for (int r = 0; r < 4; r++) {
        int b = (((lane >> 4) & 3) << 2) + r;
        float v = acc[r];
        bf16t hh = (bf16t)v;
        H[b * DD + swz(b, n)] = hh;
        L[b * DD + swz(b, n)] = (bf16t)(v - (float)hh);
    }
}

// bf16 [16][128] row-major global -> swizzled LDS hi plane (lo = 0). 512 threads.
__device__ __forceinline__ void stage_rowsB(const bf16t* __restrict__ src,
                                            bf16t* __restrict__ H, bf16t* __restrict__ L, int tid) {
    int b  = tid >> 5;
    int j0 = (tid & 31) << 2;
    bf16x4 v = *(const bf16x4*)(src + b * DD + j0);
    *(bf16x4*)(H + b * DD + swz(b, j0)) = v;
    bf16x4 z;
    z[0] = z[1] = z[2] = z[3] = (bf16t)0.f;
    *(bf16x4*)(L + b * DD + swz(b, j0)) = z;
}

__device__ __forceinline__ f32x4 load_accfragB(const bf16t* __restrict__ src, int lane, int w) {
    int n = (w << 4) + (lane & 15);
    f32x4 a;
#pragma unroll
    for (int r = 0; r < 4; r++) {
        int b = (((lane >> 4) & 3) << 2) + r;
        a[r] = (float)src[b * DD + n];
    }
    return a;
}

__device__ __forceinline__ void store_accfragB(bf16t* __restrict__ dst, int lane, int w,
                                               f32x4 a, long rs) {
    int n = (w << 4) + (lane & 15);
#pragma unroll
    for (int r = 0; r < 4; r++) {
        int b = (((lane >> 4) & 3) << 2) + r;
        dst[(long)b * rs + n] = (bf16t)a[r];
    }
}

__device__ __forceinline__ void store_accfrag(float* __restrict__ dst, int lane, int w,
                                              f32x4 a, long rs) {
    int n = (w << 4) + (lane & 15);
#pragma unroll
    for (int r = 0; r < 4; r++) {
        int b = (((lane >> 4) & 3) << 2) + r;
        dst[(long)b * rs + n] = a[r];
    }
}

// ---------------- one-block 128x128x128 matmul: OUT = L*R (+Dm), fp32 + optional bf16 pack ----
// 8 waves, wave w owns output cols [16w,16w+16); loops all 8 row-tiles.
__device__ void matmul128(const float* __restrict__ L, const float* __restrict__ R,
                          const float* __restrict__ Dm, float* __restrict__ outF,
                          bf16t* __restrict__ pack, int lane, int w) {
    Frag fB;
    load_frag_N(R, lane, w, fB);   // B-op[k][n] = R[k][n]
    int ln = lane & 15, kq = (lane >> 4) & 3;
#pragma unroll
    for (int mt = 0; mt < 8; mt++) {
        Frag fL;
        load_frag_T(L, lane, mt, fL);  // A-op rows of L
        f32x4 ax = {0,0,0,0}, ax2 = {0,0,0,0};
#pragma unroll
        for (int q = 0; q < 4; q++) {
            ax  = MFMA(fL.h[q], fB.h[q], ax);
            ax2 = MFMA(fL.l[q], fB.h[q], ax2);
            ax2 = MFMA(fL.h[q], fB.l[q], ax2);
        }
        f32x4 a = ax + ax2;
        int n = (w << 4) + ln;
#pragma unroll
        for (int r = 0; r < 4; r++) {
            int i = mt * 16 + kq * 4 + r;
            float v = a[r] + (Dm ? Dm[i * DD + n] : 0.f);
            if (outF) outF[i * DD + n] = v;
            if (pack) pack[i * DD + n] = (bf16t)v;
        }
    }
}

// ---------------- prep chain (log depth): Kpack[j] = A^{15-j} B ----------------
__global__ __launch_bounds__(512, 2) void k_prepA(const float* __restrict__ A, const float* __restrict__ B,
                                                  const float* __restrict__ C, const float* __restrict__ D,
                                                  float* A2, float* Gm, float* Hm, float* S1, bf16t* Kpk) {
    int tid = threadIdx.x, lane = tid & 63, w = tid >> 6;
    if      (blockIdx.x == 0) matmul128(A, A, nullptr, A2, nullptr, lane, w);
    else if (blockIdx.x == 1) matmul128(C, A, nullptr, Gm, nullptr, lane, w);
    else if (blockIdx.x == 2) matmul128(C, B, D, Hm, nullptr, lane, w);
    else {
        matmul128(A, B, nullptr, S1, Kpk + 14 * 16384, lane, w);   // S1 -> slot 14
        for (int i = tid; i < 16384; i += 512) Kpk[15 * 16384 + i] = (bf16t)B[i];  // S0=B -> slot 15
    }
}

__global__ __launch_bounds__(512, 2) void k_prepB(const float* __restrict__ B, const float* __restrict__ A2,
                                                  const float* __restrict__ S1,
                                                  float* A4, float* S2m, float* S3m, bf16t* Kpk) {
    int lane = threadIdx.x & 63, w = threadIdx.x >> 6;
    if      (blockIdx.x == 0) matmul128(A2, A2, nullptr, A4,  nullptr,           lane, w);
    else if (blockIdx.x == 1) matmul128(A2, B,  nullptr, S2m, Kpk + 13 * 16384,  lane, w);
    else                      matmul128(A2, S1, nullptr, S3m, Kpk + 12 * 16384,  lane, w);
}

__global__ __launch_bounds__(512, 2) void k_prepC(const float* __restrict__ B, const float* __restrict__ A4,
                                                  const float* __restrict__ S1, const float* __restrict__ S2m,
                                                  const float* __restrict__ S3m,
                                                  float* A8, float* S4m, float* S5m, float* S6m, float* S7m,
                                                  bf16t* Kpk) {
    int lane = threadIdx.x & 63, w = threadIdx.x >> 6;
    if      (blockIdx.x == 0) matmul128(A4, A4,  nullptr, A8,  nullptr,          lane, w);
    else if (blockIdx.x == 1) matmul128(A4, B,   nullptr, S4m, Kpk + 11 * 16384, lane, w);
    else if (blockIdx.x == 2) matmul128(A4, S1,  nullptr, S5m, Kpk + 10 * 16384, lane, w);
    else if (blockIdx.x == 3) matmul128(A4, S2m, nullptr, S6m, Kpk + 9 * 16384,  lane, w);
    else                      matmul128(A4, S3m, nullptr, S7m, Kpk + 8 * 16384,  lane, w);
}

__global__ __launch_bounds__(512, 2) void k_prepD(const float* __restrict__ B, const float* __restrict__ A8,
                                                  const float* __restrict__ S1, const float* __restrict__ S2m,
                                                  const float* __restrict__ S3m, const float* __restrict__ S4m,
                                                  const float* __restrict__ S5m, const float* __restrict__ S6m,
                                                  const float* __restrict__ S7m,
                                                  float* Pm, bf16t* Kpk) {
    int lane = threadIdx.x & 63, w = threadIdx.x >> 6;
    if (blockIdx.x == 0) { matmul128(A8, A8, nullptr, Pm, nullptr, lane, w); return; }
    const float* Ss[8] = {B, S1, S2m, S3m, S4m, S5m, S6m, S7m};
    int p = blockIdx.x - 1;                       // S_{8+p} = A8 * S_p -> slot 7-p
    matmul128(A8, Ss[p], nullptr, nullptr, Kpk + (7 - p) * 16384, lane, w);
}

// ---------------- pass1: E_c = U_c @ Kbig  (pure GEMM, bf16 E out) ----------------
__global__ __launch_bounds__(256, 4) void k_pass1(const float* __restrict__ u,
                                                  const bf16t* __restrict__ Kpk,
                                                  bf16t* __restrict__ E) {
    int tid = threadIdx.x, lane = tid & 63, w = tid >> 6;   // w in 0..3
    int b = lane & 15, kg = (lane >> 4) & 3;
    long c = blockIdx.x;
    const float* ur = u + (long)b * SEQ * DD + c * CL * DD;
    f32x4 a0 = {0,0,0,0}, a1 = {0,0,0,0};
#pragma unroll 4
    for (int ki = 0; ki < 64; ki++) {
        const float* p = ur + ki * 32 + kg * 8;
        float4 v0 = *(const float4*)p;
        float4 v1 = *(const float4*)(p + 4);
        bf16x8 uf;
        uf[0] = (bf16t)v0.x; uf[1] = (bf16t)v0.y; uf[2] = (bf16t)v0.z; uf[3] = (bf16t)v0.w;
        uf[4] = (bf16t)v1.x; uf[5] = (bf16t)v1.y; uf[6] = (bf16t)v1.z; uf[7] = (bf16t)v1.w;
        const bf16t* kp = Kpk + (((ki >> 2) * 128 + w * 32 + b) << 7) + (ki & 3) * 32 + kg * 8;
        bf16x8 k0 = *(const bf16x8*)kp;
        bf16x8 k1 = *(const bf16x8*)(kp + 16 * 128);
        a0 = MFMA(uf, k0, a0);
        a1 = MFMA(uf, k1, a1);
    }
    bf16t* eb = E + c * (BS * DD);
#pragma unroll
    for (int r = 0; r < 4; r++) {
        eb[(kg * 4 + r) * DD + w * 32 + b]      = (bf16t)a0[r];
        eb[(kg * 4 + r) * DD + w * 32 + 16 + b] = (bf16t)a1[r];
    }
}

// ---------------- k_group: E2[g] over 16 chunks; ident blocks -> Pg = P^16 ----------------
__global__ __launch_bounds__(512, 2) void k_group(const bf16t* __restrict__ E,
                                                  const float* __restrict__ Pm,
                                                  bf16t* __restrict__ E2,
                                                  float* __restrict__ Pg) {
    __shared__ __align__(16) bf16t Xh[2][BS * DD], Xl[2][BS * DD];
    int tid = threadIdx.x, lane = tid & 63, w = tid >> 6;
    bool ident = blockIdx.x >= NG;
    int g2 = blockIdx.x - NG;
    Frag fP;
    load_frag_T(Pm, lane, w, fP);   // B-op[k][n] = P[n][k]  (X <- X P^T)
    for (int i = tid; i < BS * DD; i += 512) {
        int b = i >> 7, j = swz(b, i & 127);
        Xh[0][i] = (bf16t)((ident && j == g2 * 16 + b) ? 1.f : 0.f);
        Xl[0][i] = (bf16t)0.f;
    }
    __syncthreads();
    int p = 0, g = blockIdx.x;
    f32x4 acc = {0,0,0,0};
    for (int r = 0; r < GRP; r++) {
        f32x4 a1 = {0,0,0,0}, a2 = {0,0,0,0};
        if (!ident) a1 = load_accfragB(E + (long)(g * GRP + r) * BS * DD, lane, w);
#pragma unroll
        for (int q = 0; q < 4; q++) {
            bf16x8 xh = afrag(Xh[p], lane, q), xl = afrag(Xl[p], lane, q);
            a1 = MFMA(xh, fP.h[q], a1);
            a2 = MFMA(xl, fP.h[q], a2);
            a1 = MFMA(xh, fP.l[q], a1);
        }
        acc = a1 + a2;
        if (r + 1 < GRP) {
            put_state(Xh[p ^ 1], Xl[p ^ 1], lane, w, acc);
            step_barrier();
            p ^= 1;
        }
    }
    if (!ident) store_accfragB(E2 + (long)g * BS * DD, lane, w, acc, DD);
    else        store_accfrag(Pg + (long)g2 * 16 * DD, lane, w, acc, DD);  // holds (P^16)^T
}

// ---------------- k_top: group entry states S2[g] ----------------
__global__ __launch_bounds__(512, 2) void k_top(const bf16t* __restrict__ E2,
                                                const float* __restrict__ Pg,
                                                bf16t* __restrict__ S2) {
    __shared__ __align__(16) bf16t Xh[2][BS * DD], Xl[2][BS * DD];
    int tid = threadIdx.x, lane = tid & 63, w = tid >> 6;
    Frag fP;
    load_frag_N(Pg, lane, w, fP);   // Pg buffer is pre-transposed
    for (int i = tid; i < BS * DD; i += 512) {
        Xh[0][i] = (bf16t)0.f;
        Xl[0][i] = (bf16t)0.f;
    }
    __syncthreads();
    int p = 0;
    f32x4 T = {0,0,0,0};
    for (int g = 0; g < NG; g++) {
        store_accfragB(S2 + (long)g * BS * DD, lane, w, T, DD);
        if (g + 1 == NG) break;
        f32x4 a1 = load_accfragB(E2 + (long)g * BS * DD, lane, w), a2 = {0,0,0,0};
#pragma unroll
        for (int q = 0; q < 4; q++) {
            bf16x8 xh = afrag(Xh[p], lane, q), xl = afrag(Xl[p], lane, q);
            a1 = MFMA(xh, fP.h[q], a1);
            a2 = MFMA(xl, fP.h[q], a2);
            a1 = MFMA(xh, fP.l[q], a1);
        }
        T = a1 + a2;
        put_state(Xh[p ^ 1], Xl[p ^ 1], lane, w, T);
        step_barrier();
        p ^= 1;
    }
}

// ---------------- k_fix: chunk entry states S[c], in place over E ----------------
__global__ __launch_bounds__(512, 2) void k_fix(bf16t* __restrict__ E,
                                                const float* __restrict__ Pm,
                                                const bf16t* __restrict__ S2) {
    __shared__ __align__(16) bf16t Xh[2][BS * DD], Xl[2][BS * DD];
    int tid = threadIdx.x, lane = tid & 63, w = tid >> 6;
    int g = blockIdx.x;
    Frag fP;
    load_frag_T(Pm, lane, w, fP);
    stage_rowsB(S2 + (long)g * BS * DD, Xh[0], Xl[0], tid);
    f32x4 T = load_accfragB(S2 + (long)g * BS * DD, lane, w);
    __syncthreads();
    int p = 0;
    for (int r = 0; r < GRP; r++) {
        long cc = (long)(g * GRP + r) * BS * DD;
        f32x4 a1 = load_accfragB(E + cc, lane, w);      // E[c] before overwrite
        store_accfragB(E + cc, lane, w, T, DD);         // S[c] = entry state
        if (r + 1 == GRP) break;
        f32x4 a2 = {0,0,0,0};
#pragma unroll
        for (int q = 0; q < 4; q++) {
            bf16x8 xh = afrag(Xh[p], lane, q), xl = afrag(Xl[p], lane, q);
            a1 = MFMA(xh, fP.h[q], a1);
            a2 = MFMA(xl, fP.h[q], a2);
            a1 = MFMA(xh, fP.l[q], a1);
        }
        T = a1 + a2;
        put_state(Xh[p ^ 1], Xl[p ^ 1], lane, w, T);
        step_barrier();
        p ^= 1;
    }
}

// ---------------- pass2: final 16-step scan, u pre-staged, fused y ----------------
__global__ __launch_bounds__(512, 2) void k_pass2(const float* __restrict__ u,
                                                  const float* __restrict__ Am,
                                                  const float* __restrict__ Bm,
                                                  const float* __restrict__ Gm,
                                                  const float* __restrict__ Hm,
                                                  const bf16t* __restrict__ S,
                                                  float* __restrict__ out) {
    __shared__ __align__(16) bf16t Uh[CL * BS * DD];               // 64 KB
    __shared__ __align__(16) bf16t Xh[2][BS * DD], Xl[2][BS * DD]; // 16 KB
    int tid = threadIdx.x, lane = tid & 63, w = tid >> 6;
    long c = blockIdx.x;
    Frag fA; FragH fB, fG, fH;
    load_frag_T(Am, lane, w, fA);
    load_frag_T_h(Bm, lane, w, fB);
    load_frag_T_h(Gm, lane, w, fG);
    load_frag_T_h(Hm, lane, w, fH);
    stage_rowsB(S + c * (BS * DD), Xh[0], Xl[0], tid);
    {
        int b_ = tid >> 5, j0_ = (tid & 31) << 2;
        const float* ub = u + (long)b_ * SEQ * DD + c * CL * DD + j0_;
        bf16t* uw = Uh + b_ * DD + swz(b_, j0_);
#pragma unroll
        for (int j = 0; j < CL; j++) {
            float4 v = *(const float4*)(ub + j * DD);
            bf16x4 h;
            h[0] = (bf16t)v.x; h[1] = (bf16t)v.y; h[2] = (bf16t)v.z; h[3] = (bf16t)v.w;
            *(bf16x4*)(uw + j * (BS * DD)) = h;
        }
    }
    step_barrier();
#pragma unroll
    for (int t = 0; t < CL; t++) {
        f32x4 ax = {0,0,0,0}, axb = {0,0,0,0}, ax2 = {0,0,0,0}, ax2b = {0,0,0,0};
        f32x4 ay = {0,0,0,0}, ayb = {0,0,0,0};
#pragma unroll
        for (int q = 0; q < 4; q++) {
            bf16x8 xh = afrag(Xh[t & 1], lane, q);
            bf16x8 xl = afrag(Xl[t & 1], lane, q);
            bf16x8 uh = afrag(Uh + t * (BS * DD), lane, q);
            if (t + 1 < CL) {
                ax   = MFMA(xh, fA.h[q], ax);
                axb  = MFMA(uh, fB.h[q], axb);
                ax2  = MFMA(xl, fA.h[q], ax2);
                ax2b = MFMA(xh, fA.l[q], ax2b);
            }
            ay  = MFMA(xh, fG.h[q], ay);
            ay  = MFMA(xl, fG.h[q], ay);
            ayb = MFMA(uh, fH.h[q], ayb);
        }
        f32x4 y = ay + ayb;
        store_accfrag(out + (c * CL + t) * DD, lane, w, y, (long)SEQ * DD);
        if (t + 1 < CL) {
            f32x4 xnew = (ax + axb) + (ax2 + ax2b);
            put_state(Xh[(t + 1) & 1], Xl[(t + 1) & 1], lane, w, xnew);
            step_barrier();
        }
    }
}

extern "C" void kernel_launch(void* const* d_in, const int* in_sizes, int n_in,
                              void* d_out, int out_size, void* d_ws, size_t ws_size,
                              hipStream_t stream) {
    (void)in_sizes; (void)n_in; (void)out_size; (void)ws_size;
    const float* u = (const float*)d_in[0];
    const float* A = (const float*)d_in[1];
    const float* B = (const float*)d_in[2];
    const float* C = (const float*)d_in[3];
    const float* D = (const float*)d_in[4];
    float* out = (float*)d_out;
    float* fp  = (float*)d_ws;
    // ws (floats): 14 x 16384 fp32 matrices + bf16 regions; total ~3.8 MB
    float* A2  = fp;             fp += 16384;
    float* A4  = fp;             fp += 16384;
    float* A8  = fp;             fp += 16384;
    float* Pm  = fp;             fp += 16384;
    float* Pg  = fp;             fp += 16384;
    float* Gm  = fp;             fp += 16384;
    float* Hm  = fp;             fp += 16384;
    float* S1  = fp;             fp += 16384;
    float* S2m = fp;             fp += 16384;
    float* S3m = fp;             fp += 16384;
    float* S4m = fp;             fp += 16384;
    float* S5m = fp;             fp += 16384;
    float* S6m = fp;             fp += 16384;
    float* S7m = fp;             fp += 16384;
    bf16t* E   = (bf16t*)fp;     fp += 524288;   // NC*2048 bf16
    bf16t* E2  = (bf16t*)fp;     fp += 32768;    // NG*2048 bf16
    bf16t* S2b = (bf16t*)fp;     fp += 32768;    // NG*2048 bf16
    bf16t* Kpk = (bf16t*)fp;     fp += 131072;   // 16*16384 bf16

    k_prepA<<<4, 512, 0, stream>>>(A, B, C, D, A2, Gm, Hm, S1, Kpk);
    k_prepB<<<3, 512, 0, stream>>>(B, A2, S1, A4, S2m, S3m, Kpk);
    k_prepC<<<5, 512, 0, stream>>>(B, A4, S1, S2m, S3m, A8, S4m, S5m, S6m, S7m, Kpk);
    k_prepD<<<9, 512, 0, stream>>>(B, A8, S1, S2m, S3m, S4m, S5m, S6m, S7m, Pm, Kpk);
    k_pass1<<<NC, 256, 0, stream>>>(u, Kpk, E);
    k_group<<<NG + 8, 512, 0, stream>>>(E, Pm, E2, Pg);
    k_top  <<<1, 512, 0, stream>>>(E2, Pg, S2b);
    k_fix  <<<NG, 512, 0, stream>>>(E, Pm, S2b);
    k_pass2<<<NC, 512, 0, stream>>>(u, A, B, Gm, Hm, E, out);
}